// Round 6
// baseline (11502.535 us; speedup 1.0000x reference)
//
#include <hip/hip_runtime.h>

// LSTM scan, persistent, XCD-LOCAL groups + split-bf16 MFMA. T=512,B=64,D=256,H=512.
// 8 groups x 32 blocks; group g = XCD g (blocks land round-robin: XCD=bid%8).
// Group owns 8 batches; block owns 16 units; wave w = gate w (i,f,g,o).
// h exchange through the COHERENT per-XCD L2: stores write-through (sc0 sc1),
// polls sc0-only (L2-hit ~200cy, no LLC RTT). Escalates to sc1 after 64 misses
// so correctness never depends on the XCD mapping. Data-driven sync (poison).
// Matmul: mfma_f32_16x16x32_bf16, 3-chain split (Whi*vhi + Wlo*vhi + Whi*vlo)
// => ~f32 accuracy. Weights live in VGPRs as bf16 fragments (192/thread).

#define TSTEPS 512
#define BATCH 64
#define DIN 256
#define HID 512
#define KTOT 768
#define NB 8                 // batches per group
#define NU 16                // units per block
#define VST 776              // bf16 per v row; stride16=97 (odd mod 8 -> spread)
#define POISON 0x7f7f7f7fu   // 3.39e38f: h in (-1,1) can never be this

typedef __attribute__((ext_vector_type(8))) short bf16x8;
typedef __attribute__((ext_vector_type(4))) float f32x4;

__device__ __forceinline__ float4 l2_load4(const float* p) {   // bypass L1, hit XCD L2
    float4 r; asm volatile("global_load_dwordx4 %0, %1, off sc0" : "=v"(r) : "v"(p)); return r;
}
__device__ __forceinline__ float4 llc_load4(const float* p) {  // bypass to LLC (fallback)
    float4 r; asm volatile("global_load_dwordx4 %0, %1, off sc0 sc1" : "=v"(r) : "v"(p)); return r;
}
__device__ __forceinline__ void llc_store1(float* p, float v) { // write-through L2+LLC
    asm volatile("global_store_dword %0, %1, off sc0 sc1" :: "v"(p), "v"(v) : "memory");
}
__device__ __forceinline__ unsigned short f2bf(float f) {       // RNE float->bf16
    unsigned u = __float_as_uint(f);
    return (unsigned short)((u + 0x7fffu + ((u >> 16) & 1u)) >> 16);
}

__global__ __launch_bounds__(256, 1)
void lstm_persistent(const float* __restrict__ seqs,
                     const float* __restrict__ h0,
                     const float* __restrict__ c0,
                     const float* __restrict__ Wi, const float* __restrict__ bi,
                     const float* __restrict__ Wf, const float* __restrict__ bff,
                     const float* __restrict__ Wg, const float* __restrict__ bg,
                     const float* __restrict__ Wo, const float* __restrict__ bo,
                     float* __restrict__ out)   // [T+1][B][H] then cT [B][H]
{
    __shared__ __align__(16) short vhi[NB * VST];   // 12416 B  [h(512) | x(256)] bf16-hi
    __shared__ __align__(16) short vlo[NB * VST];   // 12416 B  residual lo
    __shared__ float red[4][16][12];                // 3072 B   gate partials [gate][u][b]
    __shared__ float c_s[128];                      // [u + 16*b]
    __shared__ float bias_s[64];                    // [gate*16 + u]

    const int tid = threadIdx.x;
    const int bid = blockIdx.x;
    const int g    = bid & 7;        // group == XCD (round-robin dispatch)
    const int rblk = bid >> 3;       // 0..31
    const int b0 = g * NB;
    const int u0 = rblk * NU;

    const int w  = tid >> 6;         // wave = gate
    const int l  = tid & 63;
    const int n16  = l & 15;         // MFMA m/n lane index
    const int khi  = (l >> 4) & 3;   // MFMA k-group
    const int bbr  = l & 7;          // B-frag batch row (lanes 8-15 duplicate)

    // ---- weights -> bf16 fragments in registers (once) ----
    const float* Wsel = (w == 0) ? Wi : (w == 1) ? Wf : (w == 2) ? Wg : Wo;
    const float* wrow = Wsel + (size_t)(u0 + n16) * KTOT;
    bf16x8 whi[24], wlo[24];
#pragma unroll
    for (int kt = 0; kt < 24; ++kt) {
        const int k0 = kt * 32 + khi * 8;
        const float4 a = *reinterpret_cast<const float4*>(wrow + k0);
        const float4 b = *reinterpret_cast<const float4*>(wrow + k0 + 4);
        const float vals[8] = {a.x, a.y, a.z, a.w, b.x, b.y, b.z, b.w};
        bf16x8 h8, l8;
#pragma unroll
        for (int i = 0; i < 8; ++i) {
            const unsigned short hv = f2bf(vals[i]);
            const float hf = __uint_as_float((unsigned)hv << 16);
            h8[i] = (short)hv;
            l8[i] = (short)f2bf(vals[i] - hf);
        }
        whi[kt] = h8; wlo[kt] = l8;
    }

    if (tid < 64) {   // bias [gate][u]
        const int gg = tid >> 4, uu = tid & 15;
        const float* bsel = (gg == 0) ? bi : (gg == 1) ? bff : (gg == 2) ? bg : bo;
        bias_s[tid] = bsel[u0 + uu];
    }
    if (tid < 128) {  // c init + allhidden[0] = h0 slice
        const int uu = tid & 15, bb = tid >> 4;
        c_s[tid] = c0[(size_t)(b0 + bb) * HID + u0 + uu];
        out[(size_t)(b0 + bb) * HID + u0 + uu] = h0[(size_t)(b0 + bb) * HID + u0 + uu];
    }

    // ---- stage (h0, x0) -> LDS hi/lo (plain cached loads) ----
    {   // h part: thread -> (b = tid>>5, k0 = (tid&31)*16)
        const int b = tid >> 5, k0 = (tid & 31) * 16;
        const float* hp = h0 + (size_t)(b0 + b) * HID + k0;
        float hv[16];
#pragma unroll
        for (int i = 0; i < 4; ++i) {
            const float4 t4 = reinterpret_cast<const float4*>(hp)[i];
            hv[4*i] = t4.x; hv[4*i+1] = t4.y; hv[4*i+2] = t4.z; hv[4*i+3] = t4.w;
        }
        bf16x8 h8a, h8b, l8a, l8b;
#pragma unroll
        for (int i = 0; i < 8; ++i) {
            unsigned short hv1 = f2bf(hv[i]);
            h8a[i] = (short)hv1; l8a[i] = (short)f2bf(hv[i] - __uint_as_float((unsigned)hv1 << 16));
            unsigned short hv2 = f2bf(hv[8+i]);
            h8b[i] = (short)hv2; l8b[i] = (short)f2bf(hv[8+i] - __uint_as_float((unsigned)hv2 << 16));
        }
        char* vhb = (char*)vhi + b * (VST*2) + k0 * 2;
        char* vlb = (char*)vlo + b * (VST*2) + k0 * 2;
        *reinterpret_cast<bf16x8*>(vhb)      = h8a;
        *reinterpret_cast<bf16x8*>(vhb + 16) = h8b;
        *reinterpret_cast<bf16x8*>(vlb)      = l8a;
        *reinterpret_cast<bf16x8*>(vlb + 16) = l8b;
    }
    if (tid < 128) {  // x part: (b = tid>>4, kx = (tid&15)*16)
        const int b = tid >> 4, kx = (tid & 15) * 16;
        const float* xp = seqs + (size_t)(b0 + b) * DIN + kx;
        float xv[16];
#pragma unroll
        for (int i = 0; i < 4; ++i) {
            const float4 t4 = reinterpret_cast<const float4*>(xp)[i];
            xv[4*i] = t4.x; xv[4*i+1] = t4.y; xv[4*i+2] = t4.z; xv[4*i+3] = t4.w;
        }
        bf16x8 h8a, h8b, l8a, l8b;
#pragma unroll
        for (int i = 0; i < 8; ++i) {
            unsigned short hv1 = f2bf(xv[i]);
            h8a[i] = (short)hv1; l8a[i] = (short)f2bf(xv[i] - __uint_as_float((unsigned)hv1 << 16));
            unsigned short hv2 = f2bf(xv[8+i]);
            h8b[i] = (short)hv2; l8b[i] = (short)f2bf(xv[8+i] - __uint_as_float((unsigned)hv2 << 16));
        }
        char* vhb = (char*)vhi + b * (VST*2) + (HID + kx) * 2;
        char* vlb = (char*)vlo + b * (VST*2) + (HID + kx) * 2;
        *reinterpret_cast<bf16x8*>(vhb)      = h8a;
        *reinterpret_cast<bf16x8*>(vhb + 16) = h8b;
        *reinterpret_cast<bf16x8*>(vlb)      = l8a;
        *reinterpret_cast<bf16x8*>(vlb + 16) = l8b;
    }

    for (int t = 0; t < TSTEPS; ++t) {
        __syncthreads();   // v_t staged

        // T14: issue x_{t+1} loads early; they complete under the MFMA phase
        float4 xr[4];
        const bool do_stage = (t + 1 < TSTEPS);
        if (do_stage && tid < 128) {
            const int b = tid >> 4, kx = (tid & 15) * 16;
            const float* xp = seqs + (size_t)(t + 1) * BATCH * DIN + (size_t)(b0 + b) * DIN + kx;
#pragma unroll
            for (int i = 0; i < 4; ++i) xr[i] = reinterpret_cast<const float4*>(xp)[i];
        }

        // ---- MFMA: D = Whi*vhi + Wlo*vhi + Whi*vlo  (per-wave 16x16, K=768) ----
        f32x4 aA = {0.f,0.f,0.f,0.f}, aB = {0.f,0.f,0.f,0.f}, aC = {0.f,0.f,0.f,0.f};
        const char* bhp = (const char*)vhi + bbr * (VST*2) + khi * 16;
        const char* blp = (const char*)vlo + bbr * (VST*2) + khi * 16;
#pragma unroll
        for (int kt = 0; kt < 24; ++kt) {
            const bf16x8 bh = *reinterpret_cast<const bf16x8*>(bhp + kt * 64);
            const bf16x8 bl = *reinterpret_cast<const bf16x8*>(blp + kt * 64);
            aA = __builtin_amdgcn_mfma_f32_16x16x32_bf16(whi[kt], bh, aA, 0, 0, 0);
            aB = __builtin_amdgcn_mfma_f32_16x16x32_bf16(wlo[kt], bh, aB, 0, 0, 0);
            aC = __builtin_amdgcn_mfma_f32_16x16x32_bf16(whi[kt], bl, aC, 0, 0, 0);
        }
        const f32x4 gAcc = aA + aB + aC;
        // D layout: row(unit) = khi*4 + r, col(batch) = l&15 (keep cols < 8)
        if (n16 < 8) {
#pragma unroll
            for (int r = 0; r < 4; ++r)
                red[w][khi * 4 + r][n16] = gAcc[r];
        }
        __syncthreads();   // red ready; all v reads done (v free to restage)

        // ---- elementwise gates + state update + write-through h store ----
        if (tid < 128) {
            const int uu = tid & 15, bb = tid >> 4;
            const float gi = red[0][uu][bb] + bias_s[uu];
            const float gf = red[1][uu][bb] + bias_s[16 + uu];
            const float gG = red[2][uu][bb] + bias_s[32 + uu];
            const float go = red[3][uu][bb] + bias_s[48 + uu];
            const float i_ = 1.f / (1.f + __expf(-gi));
            const float f_ = 1.f / (1.f + __expf(-gf));
            const float o_ = 1.f / (1.f + __expf(-go));
            float eg = __expf(-2.f * fabsf(gG));
            float tg = (1.f - eg) / (1.f + eg);
            tg = (gG < 0.f) ? -tg : tg;
            const float cn = f_ * c_s[tid] + i_ * tg;
            c_s[tid] = cn;
            float ec = __expf(-2.f * fabsf(cn));
            float tc = (1.f - ec) / (1.f + ec);
            tc = (cn < 0.f) ? -tc : tc;
            const float hn = o_ * tc;
            llc_store1(out + (size_t)(t + 1) * BATCH * HID + (size_t)(b0 + bb) * HID + u0 + uu, hn);
            if (t == TSTEPS - 1)
                out[(size_t)(TSTEPS + 1) * BATCH * HID + (size_t)(b0 + bb) * HID + u0 + uu] = cn;
        }

        if (do_stage) {
            // ---- x_{t+1}: cvt regs -> LDS hi/lo ----
            if (tid < 128) {
                const int b = tid >> 4, kx = (tid & 15) * 16;
                float xv[16];
#pragma unroll
                for (int i = 0; i < 4; ++i) {
                    xv[4*i] = xr[i].x; xv[4*i+1] = xr[i].y; xv[4*i+2] = xr[i].z; xv[4*i+3] = xr[i].w;
                }
                bf16x8 h8a, h8b, l8a, l8b;
#pragma unroll
                for (int i = 0; i < 8; ++i) {
                    unsigned short hv1 = f2bf(xv[i]);
                    h8a[i] = (short)hv1; l8a[i] = (short)f2bf(xv[i] - __uint_as_float((unsigned)hv1 << 16));
                    unsigned short hv2 = f2bf(xv[8+i]);
                    h8b[i] = (short)hv2; l8b[i] = (short)f2bf(xv[8+i] - __uint_as_float((unsigned)hv2 << 16));
                }
                char* vhb = (char*)vhi + b * (VST*2) + (HID + kx) * 2;
                char* vlb = (char*)vlo + b * (VST*2) + (HID + kx) * 2;
                *reinterpret_cast<bf16x8*>(vhb)      = h8a;
                *reinterpret_cast<bf16x8*>(vhb + 16) = h8b;
                *reinterpret_cast<bf16x8*>(vlb)      = l8a;
                *reinterpret_cast<bf16x8*>(vlb + 16) = l8b;
            }
            // ---- poll + stage h_{t+1}: data IS the barrier (L2-local) ----
            const int b = tid >> 5, k0 = (tid & 31) * 16;
            const float* hp = out + (size_t)(t + 1) * BATCH * HID + (size_t)(b0 + b) * HID + k0;
            float4 hb[4];
            bool esc = false;
            unsigned miss = 0;
            for (;;) {
                if (!esc) {
#pragma unroll
                    for (int i = 0; i < 4; ++i) hb[i] = l2_load4(hp + 4 * i);
                } else {
#pragma unroll
                    for (int i = 0; i < 4; ++i) hb[i] = llc_load4(hp + 4 * i);
                }
                asm volatile("s_waitcnt vmcnt(0)" ::: "memory");
                __builtin_amdgcn_sched_barrier(0);
                bool ok = true;
#pragma unroll
                for (int i = 0; i < 4; ++i) {
                    ok &= (__float_as_uint(hb[i].x) != POISON);
                    ok &= (__float_as_uint(hb[i].y) != POISON);
                    ok &= (__float_as_uint(hb[i].z) != POISON);
                    ok &= (__float_as_uint(hb[i].w) != POISON);
                }
                if (ok) break;
                ++miss;
                if (miss == 64) esc = true;            // XCD-mapping fallback
                if (miss > (1u << 20)) break;          // bounded: never hang
                __builtin_amdgcn_s_sleep(1);
            }
            float hv[16];
#pragma unroll
            for (int i = 0; i < 4; ++i) {
                hv[4*i] = hb[i].x; hv[4*i+1] = hb[i].y; hv[4*i+2] = hb[i].z; hv[4*i+3] = hb[i].w;
            }
            bf16x8 h8a, h8b, l8a, l8b;
#pragma unroll
            for (int i = 0; i < 8; ++i) {
                unsigned short hv1 = f2bf(hv[i]);
                h8a[i] = (short)hv1; l8a[i] = (short)f2bf(hv[i] - __uint_as_float((unsigned)hv1 << 16));
                unsigned short hv2 = f2bf(hv[8+i]);
                h8b[i] = (short)hv2; l8b[i] = (short)f2bf(hv[8+i] - __uint_as_float((unsigned)hv2 << 16));
            }
            char* vhb = (char*)vhi + b * (VST*2) + k0 * 2;
            char* vlb = (char*)vlo + b * (VST*2) + k0 * 2;
            *reinterpret_cast<bf16x8*>(vhb)      = h8a;
            *reinterpret_cast<bf16x8*>(vhb + 16) = h8b;
            *reinterpret_cast<bf16x8*>(vlb)      = l8a;
            *reinterpret_cast<bf16x8*>(vlb + 16) = l8b;
        }
    }
}

extern "C" void kernel_launch(void* const* d_in, const int* in_sizes, int n_in,
                              void* d_out, int out_size, void* d_ws, size_t ws_size,
                              hipStream_t stream) {
    const float* seqs = (const float*)d_in[0];
    const float* h0   = (const float*)d_in[1];
    const float* c0   = (const float*)d_in[2];
    const float* Wi   = (const float*)d_in[3];
    const float* bi   = (const float*)d_in[4];
    const float* Wf   = (const float*)d_in[5];
    const float* bf   = (const float*)d_in[6];
    const float* Wg   = (const float*)d_in[7];
    const float* bg   = (const float*)d_in[8];
    const float* Wo   = (const float*)d_in[9];
    const float* bo   = (const float*)d_in[10];
    float* out = (float*)d_out;

    // Poison h[1..T] every launch: each element written exactly once per run,
    // so the data itself is the readiness flag (graph-replay safe).
    hipMemsetAsync((char*)out + (size_t)BATCH * HID * 4, 0x7f,
                   (size_t)TSTEPS * BATCH * HID * 4, stream);

    hipLaunchKernelGGL(lstm_persistent, dim3(256), dim3(256), 0, stream,
                       seqs, h0, c0, Wi, bi, Wf, bf, Wg, bg, Wo, bo, out);
}